// Round 6
// baseline (322.084 us; speedup 1.0000x reference)
//
#include <hip/hip_runtime.h>
#include <hip/hip_cooperative_groups.h>
#include <stdint.h>
#include <math.h>

namespace cg = cooperative_groups;

#define N_NODES 4096
#define F_DIM   256
#define BATCH   8

typedef __attribute__((ext_vector_type(8))) __bf16 bf16x8;
typedef __attribute__((ext_vector_type(4))) float  f32x4;
typedef __attribute__((ext_vector_type(8))) unsigned short u16x8;

typedef const __attribute__((address_space(1))) void* gas1_t;
typedef __attribute__((address_space(3))) void*       las3_t;

__device__ __forceinline__ void stage16(const void* g, void* l) {
  __builtin_amdgcn_global_load_lds((gas1_t)g, (las3_t)l, 16, 0, 0);
}

__device__ __forceinline__ unsigned short f2bf(float f) {
  union { float f; uint32_t u; } v; v.f = f;
  uint32_t u = v.u;
  return (unsigned short)((u + 0x7FFFu + ((u >> 16) & 1u)) >> 16); // RTNE
}
__device__ __forceinline__ float bf2f(unsigned short u) {
  union { uint32_t u; float f; } v; v.u = ((uint32_t)u) << 16;
  return v.f;
}
__device__ __forceinline__ float dinv_of(float d) {
  return d > 0.f ? 1.0f / sqrtf(d) : 0.f;
}

#define LDSB 49152  // gemm2: bytes per buffer (A 32768 + B 16384)

// ================= single cooperative kernel: all phases =================
// 256 blocks x 512 threads, 147456 B LDS, 1 block/CU (grid == CU count).
__global__ __launch_bounds__(512, 2) void k_all(
    const float* __restrict__ A,
    const float4* __restrict__ H4,
    const float* __restrict__ W,
    unsigned short* __restrict__ Sb,
    ushort4* __restrict__ Hb4,
    unsigned short* __restrict__ Wt,
    float* __restrict__ Dpart,
    float* __restrict__ dinvA,
    unsigned short* __restrict__ HWb,
    unsigned short* __restrict__ Gt,
    float* __restrict__ Out) {
  cg::grid_group grid = cg::this_grid();
  __shared__ __align__(16) unsigned short SMEM[3 * 24576];  // 147456 B
  char* sm = (char*)SMEM;
  int t = threadIdx.x;
  int bid = blockIdx.x;

  // ---------------- phase A0: H cast (grid-stride) + W transpose ----------------
#pragma unroll
  for (int it = 0; it < 16; ++it) {
    int i = (bid * 16 + it) * 512 + t;
    float4 v = H4[i];
    ushort4 o; o.x = f2bf(v.x); o.y = f2bf(v.y); o.z = f2bf(v.z); o.w = f2bf(v.w);
    Hb4[i] = o;
  }
  if (bid < 128) {
    int e = bid * 512 + t;                    // e = i*256 + o
    Wt[(e & 255) * 256 + (e >> 8)] = f2bf(W[e]);
  }

  // ---------------- phase A1: symmetrize+relu tiles + Dpart ----------------
  {
    float (*T1)[68] = (float (*)[68])sm;            // 17408 B
    float (*Tt)[67] = (float (*)[67])(sm + 17408);  // 17152 B
    for (int q = bid; q < 2080; q += 256) {
      // triangular decode: C(bi) = bi*(129-bi)/2
      int bi = (int)((129.0 - sqrt(129.0 * 129.0 - 8.0 * (double)q)) * 0.5);
      while (bi * (129 - bi) / 2 > q) --bi;
      while ((bi + 1) * (128 - bi) / 2 <= q) ++bi;
      int bj = bi + (q - bi * (129 - bi) / 2);
      int i0 = bi * 64, j0 = bj * 64;
      __syncthreads();  // previous iteration's LDS readers done
#pragma unroll
      for (int it = 0; it < 2; ++it) {
        int idx = it * 512 + t;
        int r = idx >> 4, c4 = (idx & 15) * 4;
        float4 v1 = *(const float4*)(A + (size_t)(i0 + r) * N_NODES + j0 + c4);
        *(float4*)&T1[r][c4] = v1;
        float4 v2 = *(const float4*)(A + (size_t)(j0 + r) * N_NODES + i0 + c4);
        Tt[c4 + 0][r] = v2.x; Tt[c4 + 1][r] = v2.y; Tt[c4 + 2][r] = v2.z; Tt[c4 + 3][r] = v2.w;
      }
      __syncthreads();
      int r = t >> 3, g = t & 7, c0 = g * 8;
      float vv[8]; float rp = 0.f;
      u16x8 u;
#pragma unroll
      for (int i = 0; i < 8; ++i) {
        float v = 0.5f * (T1[r][c0 + i] + Tt[r][c0 + i]);
        v = v > 0.f ? v : 0.f;
        vv[i] = v; rp += v; u[i] = f2bf(v);
      }
      *(u16x8*)&Sb[(size_t)(i0 + r) * N_NODES + j0 + c0] = u;
      rp += __shfl_xor(rp, 1); rp += __shfl_xor(rp, 2); rp += __shfl_xor(rp, 4);
      if (g == 0) Dpart[(size_t)bj * N_NODES + i0 + r] = rp;
      if (bi != bj) {
        __syncthreads();  // raw Tt reads done before overwrite
#pragma unroll
        for (int i = 0; i < 8; ++i) Tt[c0 + i][r] = vv[i];  // v^T
        __syncthreads();
        u16x8 o; float cp = 0.f;
#pragma unroll
        for (int i = 0; i < 8; ++i) { float x = Tt[r][c0 + i]; o[i] = f2bf(x); cp += x; }
        *(u16x8*)&Sb[(size_t)(j0 + r) * N_NODES + i0 + c0] = o;
        cp += __shfl_xor(cp, 1); cp += __shfl_xor(cp, 2); cp += __shfl_xor(cp, 4);
        if (g == 0) Dpart[(size_t)bi * N_NODES + j0 + r] = cp;
      }
    }
  }
  grid.sync();

  // ---------------- phase A2: D reduce -> dinvA (Dpart is L2-resident) ----------
  {
    int rl = t >> 5, l32 = t & 31;
    int row = bid * 16 + rl;
    float s = Dpart[(size_t)(2 * l32) * N_NODES + row] +
              Dpart[(size_t)(2 * l32 + 1) * N_NODES + row];
    s += __shfl_xor(s, 1); s += __shfl_xor(s, 2); s += __shfl_xor(s, 4);
    s += __shfl_xor(s, 8); s += __shfl_xor(s, 16);
    if (l32 == 0) dinvA[row] = dinv_of(s);
  }
  grid.sync();

  // ---------------- phase B: gemm1 (single-shot K=256), 2 jobs/block ------------
  {
    unsigned short* L = (unsigned short*)sm;  // As 64KB | Ws 64KB
    int lane = t & 63, r16 = lane & 15, qq = lane >> 4;
    int wave = t >> 6;
    int wm = wave >> 2, wn = wave & 3;
#pragma unroll 1
    for (int jt = 0; jt < 2; ++jt) {
      int job = bid + jt * 256;
      int nh = job & 1, my = job >> 1;
      int m0 = my * 128, n0 = nh * 128;
      __syncthreads();  // previous job's LDS readers done
#pragma unroll
      for (int i = 0; i < 8; ++i) {
        int s = i * 512 + t;
        int row = s >> 5, cl = s & 31;
        int cs = cl ^ (row & 7);
        uint32_t dst = (uint32_t)(i * 512 + (t & ~63)) * 16;
        stage16((const unsigned short*)Hb4 + (size_t)(m0 + row) * 256 + cs * 8, sm + dst);
        stage16(Wt + (size_t)(n0 + row) * 256 + cs * 8, sm + 65536 + dst);
      }
      __syncthreads();

      f32x4 acc[4][2];
#pragma unroll
      for (int i = 0; i < 4; ++i)
#pragma unroll
        for (int j = 0; j < 2; ++j) acc[i][j] = f32x4{0.f, 0.f, 0.f, 0.f};

#pragma unroll
      for (int ks = 0; ks < 8; ++ks) {
        bf16x8 a[4], b[2];
#pragma unroll
        for (int mi = 0; mi < 4; ++mi) {
          int ra = wm * 64 + mi * 16 + r16;
          a[mi] = *(const bf16x8*)(sm + ra * 512 + (((ks * 4 + qq) ^ (ra & 7)) << 4));
        }
#pragma unroll
        for (int ni = 0; ni < 2; ++ni) {
          int rb = wn * 32 + ni * 16 + r16;
          b[ni] = *(const bf16x8*)(sm + 65536 + rb * 512 + (((ks * 4 + qq) ^ (rb & 7)) << 4));
        }
#pragma unroll
        for (int mi = 0; mi < 4; ++mi)
#pragma unroll
          for (int ni = 0; ni < 2; ++ni)
            acc[mi][ni] = __builtin_amdgcn_mfma_f32_16x16x32_bf16(a[mi], b[ni], acc[mi][ni], 0, 0, 0);
      }
      __syncthreads();  // done reading As before T overwrites it

      unsigned short (*T)[136] = (unsigned short (*)[136])sm;  // 34816 B
#pragma unroll
      for (int mi = 0; mi < 4; ++mi) {
        int rowl = wm * 64 + mi * 16 + qq * 4;
#pragma unroll
        for (int ni = 0; ni < 2; ++ni) {
          int coll = wn * 32 + ni * 16 + r16;
#pragma unroll
          for (int rr = 0; rr < 4; ++rr) {
            unsigned short h = f2bf(acc[mi][ni][rr]);
            HWb[(size_t)(m0 + rowl + rr) * F_DIM + (n0 + coll)] = h;
            T[coll][rowl + rr] = h;
          }
        }
      }
      __syncthreads();

      int b = m0 >> 12, nb = m0 & 4095;
#pragma unroll
      for (int i = 0; i < 4; ++i) {
        int u = i * 512 + t;
        int co = u >> 4, cs = (u & 15) * 8;
        u16x8 v = *(const u16x8*)&T[co][cs];
        float4 d0 = *(const float4*)&dinvA[nb + cs];
        float4 d1 = *(const float4*)&dinvA[nb + cs + 4];
        u16x8 w;
        w[0] = f2bf(bf2f(v[0]) * d0.x);
        w[1] = f2bf(bf2f(v[1]) * d0.y);
        w[2] = f2bf(bf2f(v[2]) * d0.z);
        w[3] = f2bf(bf2f(v[3]) * d0.w);
        w[4] = f2bf(bf2f(v[4]) * d1.x);
        w[5] = f2bf(bf2f(v[5]) * d1.y);
        w[6] = f2bf(bf2f(v[6]) * d1.z);
        w[7] = f2bf(bf2f(v[7]) * d1.w);
        *(u16x8*)&Gt[(size_t)(b * 256 + n0 + co) * N_NODES + nb + cs] = w;
      }
    }
  }
  grid.sync();

  // ---------------- phase C: gemm2 (R1/R5 proven triple-buffer pipeline) --------
  {
    const int NT = N_NODES / 64;
    int lane = t & 63, r16 = lane & 15, q = lane >> 4;
    int wave = t >> 6;
    int wm = wave >> 1, wn = wave & 1;

    int xcd = bid & 7, j = bid >> 3;
    int mt = (xcd >> 1) * 4 + (j & 3);
    int nt = (xcd & 1) * 8 + (j >> 2);
    int m0 = mt * 256, n0 = nt * 128;

    const char* aSrc[4]; const char* bSrc[2];
    uint32_t aDst[4], bDst[2];
#pragma unroll
    for (int i = 0; i < 4; ++i) {
      int slot = i * 512 + t;
      int row = slot >> 3;
      int c = (slot & 7) ^ (row & 7);
      aSrc[i] = (const char*)Sb + (size_t)(m0 + row) * 8192 + c * 16;
      aDst[i] = (uint32_t)(i * 512 + (t & ~63)) * 16;
    }
#pragma unroll
    for (int i = 0; i < 2; ++i) {
      int slot = i * 512 + t;
      int row = slot >> 3;
      int c = (slot & 7) ^ (row & 7);
      bSrc[i] = (const char*)Gt + (size_t)(n0 + row) * 8192 + c * 16;
      bDst[i] = 32768u + (uint32_t)(i * 512 + (t & ~63)) * 16;
    }

    int aoff[4][2], boff[4][2];
#pragma unroll
    for (int mi = 0; mi < 4; ++mi) {
      int ra = wm * 64 + mi * 16 + r16;
#pragma unroll
      for (int ks = 0; ks < 2; ++ks)
        aoff[mi][ks] = ra * 128 + (((ks * 4 + q) ^ (ra & 7)) << 4);
    }
#pragma unroll
    for (int ni = 0; ni < 4; ++ni) {
      int rb = wn * 64 + ni * 16 + r16;
#pragma unroll
      for (int ks = 0; ks < 2; ++ks)
        boff[ni][ks] = 32768 + rb * 128 + (((ks * 4 + q) ^ (rb & 7)) << 4);
    }

    f32x4 acc[4][4];
#pragma unroll
    for (int i = 0; i < 4; ++i)
#pragma unroll
      for (int jj = 0; jj < 4; ++jj) acc[i][jj] = f32x4{0.f, 0.f, 0.f, 0.f};

    auto stage_tile = [&](int kt2, uint32_t bufByte) {
      size_t kb = (size_t)kt2 * 128;
#pragma unroll
      for (int i = 0; i < 4; ++i)
        stage16(aSrc[i] + kb, sm + bufByte + aDst[i]);
#pragma unroll
      for (int i = 0; i < 2; ++i)
        stage16(bSrc[i] + kb, sm + bufByte + bDst[i]);
    };

    auto tile_body = [&](int kt, uint32_t cur, int mode) {
      bf16x8 aR[4][2], bR[4][2];
#pragma unroll
      for (int mi = 0; mi < 4; ++mi)
#pragma unroll
        for (int ks = 0; ks < 2; ++ks)
          aR[mi][ks] = *(const bf16x8*)(sm + cur + aoff[mi][ks]);
#pragma unroll
      for (int ni = 0; ni < 4; ++ni)
#pragma unroll
        for (int ks = 0; ks < 2; ++ks)
          bR[ni][ks] = *(const bf16x8*)(sm + cur + boff[ni][ks]);
      if (mode == 2) {
        uint32_t stg = cur + 2 * LDSB;
        if (stg >= 3 * LDSB) stg -= 3 * LDSB;
        stage_tile(kt + 2, stg);
      }
      __builtin_amdgcn_sched_barrier(0);
      __builtin_amdgcn_s_setprio(1);
#pragma unroll
      for (int ks = 0; ks < 2; ++ks)
#pragma unroll
        for (int mi = 0; mi < 4; ++mi)
#pragma unroll
          for (int ni = 0; ni < 4; ++ni)
            acc[mi][ni] = __builtin_amdgcn_mfma_f32_16x16x32_bf16(aR[mi][ks], bR[ni][ks], acc[mi][ni], 0, 0, 0);
      __builtin_amdgcn_s_setprio(0);
      if (mode == 2) {
        asm volatile("s_waitcnt vmcnt(6)" ::: "memory");
      } else if (mode == 1) {
        asm volatile("s_waitcnt vmcnt(0)" ::: "memory");
      }
      if (mode != 0) {
        __builtin_amdgcn_s_barrier();
        __builtin_amdgcn_sched_barrier(0);
      }
    };

    stage_tile(0, 0);
    stage_tile(1, LDSB);
    asm volatile("s_waitcnt vmcnt(6)" ::: "memory");
    __builtin_amdgcn_s_barrier();
    __builtin_amdgcn_sched_barrier(0);

    uint32_t cur = 0;
#pragma unroll 1
    for (int kt = 0; kt < NT - 2; ++kt) {
      tile_body(kt, cur, 2);
      cur += LDSB; if (cur == 3 * LDSB) cur = 0;
    }
    tile_body(NT - 2, cur, 1);
    cur += LDSB; if (cur == 3 * LDSB) cur = 0;
    tile_body(NT - 1, cur, 0);

    int bq = n0 >> 8;
#pragma unroll
    for (int mi = 0; mi < 4; ++mi) {
      int row = m0 + wm * 64 + mi * 16 + q * 4;
      float di[4];
#pragma unroll
      for (int rr = 0; rr < 4; ++rr) di[rr] = dinvA[row + rr];
#pragma unroll
      for (int ni = 0; ni < 4; ++ni) {
        int col = n0 + wn * 64 + ni * 16 + r16;
        int o = col & 255;
#pragma unroll
        for (int rr = 0; rr < 4; ++rr) {
          size_t oi = ((size_t)bq * N_NODES + (row + rr)) * F_DIM + o;
          float u = bf2f(HWb[oi]) - di[rr] * acc[mi][ni][rr];
          Out[oi] = u > 0.f ? u : 0.f;
        }
      }
    }
  }
}

extern "C" void kernel_launch(void* const* d_in, const int* in_sizes, int n_in,
                              void* d_out, int out_size, void* d_ws, size_t ws_size,
                              hipStream_t stream) {
  (void)in_sizes; (void)n_in; (void)out_size; (void)ws_size;
  const float* A = (const float*)d_in[2];
  const float4* H4 = (const float4*)d_in[0];
  const float* W = (const float*)d_in[1];
  float* out = (float*)d_out;

  char* ws = (char*)d_ws;
  size_t off = 0;
  auto alloc = [&](size_t bytes) {
    char* p = ws + off;
    off += (bytes + 255) & ~(size_t)255;
    return p;
  };
  float*          Dpart = (float*)alloc((size_t)64 * N_NODES * 4);                      // 1 MB
  float*          dinvA = (float*)alloc((size_t)N_NODES * 4);
  unsigned short* Sb    = (unsigned short*)alloc((size_t)N_NODES * N_NODES * 2);        // 32 MB
  unsigned short* HWb   = (unsigned short*)alloc((size_t)BATCH * N_NODES * F_DIM * 2);  // 16 MB
  unsigned short* Gt    = (unsigned short*)alloc((size_t)BATCH * F_DIM * N_NODES * 2);  // 16 MB
  unsigned short* Wt    = (unsigned short*)alloc((size_t)F_DIM * F_DIM * 2);
  ushort4*        Hb4   = (ushort4*)alloc((size_t)BATCH * N_NODES * F_DIM * 2);         // 16 MB

  void* args[] = {(void*)&A, (void*)&H4, (void*)&W, (void*)&Sb, (void*)&Hb4,
                  (void*)&Wt, (void*)&Dpart, (void*)&dinvA, (void*)&HWb,
                  (void*)&Gt, (void*)&out};
  hipLaunchCooperativeKernel((const void*)k_all, dim3(256), dim3(512), args, 0, stream);
}